// Round 5
// baseline (3753.297 us; speedup 1.0000x reference)
//
#include <hip/hip_runtime.h>

#define B_     2
#define L_     4096
#define DM     1024
#define DI     2048
#define NH     16
#define HD     128
#define NS     64      // D_STATE
#define T_     256     // CHUNK
#define NC     16      // L_/T_
#define CONVD  2176    // DI + 2*NS
#define DPROJ  4240    // DI + CONVD + NH

// ---------------- C[m,n] = sum_k A[m,k]*B[n,k], reg-prefetch + LDS double-buffer ----------------
__global__ __launch_bounds__(256) void sgemm_abt(
    const float* __restrict__ A, const float* __restrict__ Bm, float* __restrict__ C,
    int M, int N, int K, int lda, int ldb, int ldc)
{
    const int BK = 16;
    __shared__ __align__(16) float As[2][BK][128];
    __shared__ __align__(16) float Bs[2][BK][128];
    int tid = threadIdx.x;
    int m0 = blockIdx.y * 128;
    int n0 = blockIdx.x * 128;
    int ty = tid / 16, tx = tid % 16;

    float4 ra[2], rb[2];
    // global -> regs for k-tile at k0
    auto gload = [&](int k0) {
        #pragma unroll
        for (int i = 0; i < 2; i++) {
            int f = tid * 2 + i;
            int row = f >> 2, colv = f & 3;
            ra[i] = *(const float4*)(A + (size_t)(m0 + row) * lda + k0 + colv * 4);
            rb[i] = make_float4(0.f, 0.f, 0.f, 0.f);
            if (n0 + row < N)
                rb[i] = *(const float4*)(Bm + (size_t)(n0 + row) * ldb + k0 + colv * 4);
        }
    };
    // regs -> LDS buffer buf (transposed [k][m])
    auto lwrite = [&](int buf) {
        #pragma unroll
        for (int i = 0; i < 2; i++) {
            int f = tid * 2 + i;
            int row = f >> 2, colv = f & 3;
            As[buf][colv*4+0][row] = ra[i].x; As[buf][colv*4+1][row] = ra[i].y;
            As[buf][colv*4+2][row] = ra[i].z; As[buf][colv*4+3][row] = ra[i].w;
            Bs[buf][colv*4+0][row] = rb[i].x; Bs[buf][colv*4+1][row] = rb[i].y;
            Bs[buf][colv*4+2][row] = rb[i].z; Bs[buf][colv*4+3][row] = rb[i].w;
        }
    };

    float acc[8][8];
    #pragma unroll
    for (int i = 0; i < 8; i++)
        #pragma unroll
        for (int j = 0; j < 8; j++) acc[i][j] = 0.f;

    gload(0); lwrite(0);
    __syncthreads();
    int cur = 0;
    for (int k0 = 0; k0 < K; k0 += BK) {
        bool nxt = (k0 + BK) < K;
        if (nxt) gload(k0 + BK);          // issue early; latency hidden by FMA loop
        #pragma unroll
        for (int kk = 0; kk < BK; kk++) {
            float4 a0 = *(const float4*)&As[cur][kk][ty*8];
            float4 a1 = *(const float4*)&As[cur][kk][ty*8+4];
            float4 b0 = *(const float4*)&Bs[cur][kk][tx*4];
            float4 b1 = *(const float4*)&Bs[cur][kk][64 + tx*4];
            float a[8] = {a0.x,a0.y,a0.z,a0.w,a1.x,a1.y,a1.z,a1.w};
            float b[8] = {b0.x,b0.y,b0.z,b0.w,b1.x,b1.y,b1.z,b1.w};
            #pragma unroll
            for (int i = 0; i < 8; i++)
                #pragma unroll
                for (int j = 0; j < 8; j++)
                    acc[i][j] = fmaf(a[i], b[j], acc[i][j]);
        }
        if (nxt) lwrite(cur ^ 1);         // write next tile to other buffer
        __syncthreads();
        cur ^= 1;
    }
    #pragma unroll
    for (int i = 0; i < 8; i++) {
        int m = m0 + ty*8 + i;
        #pragma unroll
        for (int j = 0; j < 8; j++) {
            int n = n0 + ((j < 4) ? (tx*4 + j) : (64 + tx*4 + j - 4));
            if (n < N) C[(size_t)m * ldc + n] = acc[i][j];
        }
    }
}

// ---------------- depthwise causal conv (width 4) + bias + silu; one batch ----------------
__global__ void conv_silu(const float* __restrict__ proj, const float* __restrict__ w,
                          const float* __restrict__ bias, float* __restrict__ xbc)
{
    size_t idx = (size_t)blockIdx.x * 256 + threadIdx.x;
    if (idx >= (size_t)L_ * CONVD) return;
    int c = (int)(idx % CONVD);
    int l = (int)(idx / CONVD);
    float acc = bias[c];
    #pragma unroll
    for (int j = 0; j < 4; j++) {
        int ll = l - 3 + j;
        if (ll >= 0)
            acc = fmaf(proj[(size_t)ll * DPROJ + DI + c], w[c*4+j], acc);
    }
    acc = acc / (1.f + expf(-acc));   // silu
    xbc[(size_t)l * CONVD + c] = acc;
}

// ---------------- dt = softplus(dt_raw + bias); acs = cumsum(dt*A) within 256-chunk ----------------
__global__ __launch_bounds__(256) void dt_scan(
    const float* __restrict__ proj, const float* __restrict__ A_log,
    const float* __restrict__ dt_bias, float* __restrict__ dt_t, float* __restrict__ acs)
{
    int blk = blockIdx.x;            // c*NH + h
    int h = blk % NH;
    int c = blk / NH;
    int t = threadIdx.x;
    size_t row = (size_t)(c * T_ + t);
    float raw = proj[row * DPROJ + DI + CONVD + h] + dt_bias[h];
    float dtv = (raw > 20.f) ? raw : log1pf(expf(raw));
    float Ah = -expf(A_log[h]);
    __shared__ float buf[T_];
    buf[t] = dtv * Ah;
    __syncthreads();
    for (int off = 1; off < T_; off <<= 1) {
        float add = (t >= off) ? buf[t - off] : 0.f;
        __syncthreads();
        buf[t] += add;
        __syncthreads();
    }
    size_t o = (size_t)blk * T_ + t;
    dt_t[o] = dtv;
    acs[o]  = buf[t];
}

// ---------------- per-256-chunk states[p][n] = sum_t x[t,p]*B[t,n]*exp(acs_last-acs[t])*dt[t] ----------------
__global__ __launch_bounds__(256) void chunk_states(
    const float* __restrict__ xbc, const float* __restrict__ dt_t,
    const float* __restrict__ acs, float* __restrict__ states)
{
    int blk = blockIdx.x;            // c*NH + h
    int h = blk % NH;
    int c = blk / NH;
    int tid = threadIdx.x;
    __shared__ float coef[T_];
    __shared__ __align__(16) float xs[32][HD];
    __shared__ float Bs[32][NS + 1];
    {
        size_t o = (size_t)blk * T_;
        float last = acs[o + T_ - 1];
        coef[tid] = expf(last - acs[o + tid]) * dt_t[o + tid];
    }
    __syncthreads();
    int tx = tid % 16;   // n0 = tx*4
    int ty = tid / 16;   // p0 = ty*8
    float acc[8][4];
    #pragma unroll
    for (int i = 0; i < 8; i++)
        #pragma unroll
        for (int j = 0; j < 4; j++) acc[i][j] = 0.f;
    size_t rowbase = (size_t)(c * T_);
    for (int t0 = 0; t0 < T_; t0 += 32) {
        #pragma unroll
        for (int i = 0; i < 4; i++) {
            int idx = tid + 256 * i;
            int r = idx >> 5, cv = idx & 31;
            float4 v = *(const float4*)(xbc + (rowbase + t0 + r) * CONVD + h * HD + cv * 4);
            *(float4*)&xs[r][cv * 4] = v;
        }
        #pragma unroll
        for (int i = 0; i < 2; i++) {
            int idx = tid + 256 * i;
            int r = idx >> 4, cv = idx & 15;
            float4 v = *(const float4*)(xbc + (rowbase + t0 + r) * CONVD + DI + cv * 4);
            float wc = coef[t0 + r];
            Bs[r][cv*4+0] = v.x * wc; Bs[r][cv*4+1] = v.y * wc;
            Bs[r][cv*4+2] = v.z * wc; Bs[r][cv*4+3] = v.w * wc;
        }
        __syncthreads();
        #pragma unroll
        for (int tt = 0; tt < 32; tt++) {
            float xv[8], bv[4];
            #pragma unroll
            for (int i = 0; i < 8; i++) xv[i] = xs[tt][ty*8+i];
            #pragma unroll
            for (int j = 0; j < 4; j++) bv[j] = Bs[tt][tx*4+j];
            #pragma unroll
            for (int i = 0; i < 8; i++)
                #pragma unroll
                for (int j = 0; j < 4; j++)
                    acc[i][j] = fmaf(xv[i], bv[j], acc[i][j]);
        }
        __syncthreads();
    }
    size_t base = (size_t)blk * HD * NS;
    #pragma unroll
    for (int i = 0; i < 8; i++)
        #pragma unroll
        for (int j = 0; j < 4; j++)
            states[base + (size_t)(ty*8+i) * NS + tx*4+j] = acc[i][j];
}

// ---------------- in-place inter-chunk recurrence: states[c] <- prev[c] ----------------
__global__ __launch_bounds__(256) void prev_rec(
    float* __restrict__ states, const float* __restrict__ acs)
{
    int blk = blockIdx.x;          // h*4 + pq
    int pq = blk % 4;
    int h = blk / 4;
    int tid = threadIdx.x;
    int s = tid * 8;
    int p = pq * 32 + s / NS;
    int n0 = s % NS;
    float run[8];
    #pragma unroll
    for (int j = 0; j < 8; j++) run[j] = 0.f;
    for (int c = 0; c < NC; c++) {
        size_t ch = (size_t)(c * NH + h);
        size_t off = ch * HD * NS + (size_t)p * NS + n0;
        float sv[8];
        #pragma unroll
        for (int j = 0; j < 8; j++) sv[j] = states[off + j];
        #pragma unroll
        for (int j = 0; j < 8; j++) states[off + j] = run[j];
        float f = expf(acs[ch * T_ + T_ - 1]);
        #pragma unroll
        for (int j = 0; j < 8; j++) run[j] = sv[j] + f * run[j];
    }
}

// ---------------- fused Y with running state H in LDS; reg-prefetch of next sub-chunk ----------------
__global__ __launch_bounds__(256, 4) void y_chunk(
    const float* __restrict__ xbc, const float* __restrict__ dt_t,
    const float* __restrict__ acs, const float* __restrict__ prev,
    const float* __restrict__ D_skip, float* zy /* = proj */)
{
    int blk = blockIdx.x;          // ((c*NH)+h)*4 + pq
    int pq = blk & 3;
    int h = (blk >> 2) & 15;
    int c = blk >> 6;
    int tid = threadIdx.x;
    int tx = tid & 15;
    int ty = tid >> 4;
    int p0 = pq * 32;

    __shared__ __align__(16) float smem[9184];
    float* H     = smem;           // [32][65]
    float* Cs    = smem + 2080;    // [32][68]
    float* Bsh   = smem + 4256;    // [32][68]
    float* xs    = smem + 6432;    // [32][36]
    float* Ss    = smem + 7584;    // [32][33]
    float* acs_s = smem + 8640;    // [256]
    float* dts   = smem + 8896;    // [256]
    float* coefs = smem + 9152;    // [32]

    size_t bch = (size_t)(c * NH + h);
    size_t rowbase = (size_t)(c * T_);
    acs_s[tid] = acs[bch * T_ + tid];
    dts[tid]   = dt_t[bch * T_ + tid];

    // prefetch register file + issue helper (B:2, C:2, x:1 float4 per thread)
    float4 pB0, pB1, pC0, pC1, pX;
    int rB0 = tid >> 4, cB0 = (tid & 15) * 4;
    int rB1 = (tid + 256) >> 4, cB1 = ((tid + 256) & 15) * 4;
    int rX = tid >> 3, cX = (tid & 7) * 4;
    auto issue = [&](int s) {
        const float* base = xbc + (rowbase + s * 32) * CONVD;
        pB0 = *(const float4*)(base + (size_t)rB0 * CONVD + DI + cB0);
        pC0 = *(const float4*)(base + (size_t)rB0 * CONVD + DI + NS + cB0);
        pB1 = *(const float4*)(base + (size_t)rB1 * CONVD + DI + cB1);
        pC1 = *(const float4*)(base + (size_t)rB1 * CONVD + DI + NS + cB1);
        pX  = *(const float4*)(base + (size_t)rX * CONVD + h * HD + p0 + cX);
    };
    issue(0);                       // overlap with H init

    // H init: prev[p0..p0+31][0..63]
    #pragma unroll
    for (int i = 0; i < 8; i++) {
        int idx = tid + 256 * i;
        int p = idx >> 6, n = idx & 63;
        H[p * 65 + n] = prev[bch * (HD * NS) + (size_t)(p0 + p) * NS + n];
    }
    __syncthreads();

    float Dh = D_skip[h];

    for (int s = 0; s < 8; s++) {
        int b32 = s * 32;
        float base = (s == 0) ? 0.f : acs_s[b32 - 1];
        float aL = acs_s[b32 + 31];

        // ---- phase 1: prefetched regs -> LDS
        *(float4*)&Bsh[rB0 * 68 + cB0] = pB0;
        *(float4*)&Cs [rB0 * 68 + cB0] = pC0;
        *(float4*)&Bsh[rB1 * 68 + cB1] = pB1;
        *(float4*)&Cs [rB1 * 68 + cB1] = pC1;
        *(float4*)&xs [rX * 36 + cX]   = pX;
        if (tid < 32)
            coefs[tid] = dts[b32 + tid] * expf(aL - acs_s[b32 + tid]);
        __syncthreads();

        // issue next sub-chunk's loads + this sub-chunk's z-gate loads (hidden under P2/P3)
        if (s < 7) issue(s + 1);
        float2 pZ0 = *(const float2*)(zy + (rowbase + b32 + ty*2 + 0) * DPROJ + h * HD + p0 + tx*2);
        float2 pZ1 = *(const float2*)(zy + (rowbase + b32 + ty*2 + 1) * DPROJ + h * HD + p0 + tx*2);

        // ---- phase 2: S[q][k] = (C·B)·exp(acs[q]-acs[k])·dt[k], masked q>=k
        {
            float sv[2][2] = {{0.f,0.f},{0.f,0.f}};
            for (int n = 0; n < NS; n++) {
                float cq0 = Cs[(ty*2+0) * 68 + n];
                float cq1 = Cs[(ty*2+1) * 68 + n];
                float bk0 = Bsh[(tx*2+0) * 68 + n];
                float bk1 = Bsh[(tx*2+1) * 68 + n];
                sv[0][0] = fmaf(cq0, bk0, sv[0][0]);
                sv[0][1] = fmaf(cq0, bk1, sv[0][1]);
                sv[1][0] = fmaf(cq1, bk0, sv[1][0]);
                sv[1][1] = fmaf(cq1, bk1, sv[1][1]);
            }
            #pragma unroll
            for (int qi = 0; qi < 2; qi++) {
                int ql = ty*2 + qi;
                #pragma unroll
                for (int ki = 0; ki < 2; ki++) {
                    int kl = tx*2 + ki;
                    float val = 0.f;
                    if (ql >= kl)
                        val = sv[qi][ki] * expf(acs_s[b32+ql] - acs_s[b32+kl]) * dts[b32+kl];
                    Ss[ql * 33 + kl] = val;
                }
            }
        }
        __syncthreads();

        // ---- phase 3: Y = S·x + eq·(C·H) + D·x, gate with prefetched z, write
        {
            float acc[2][2] = {{0.f,0.f},{0.f,0.f}};
            for (int kk = 0; kk < 32; kk++) {
                float s0 = Ss[(ty*2+0) * 33 + kk];
                float s1 = Ss[(ty*2+1) * 33 + kk];
                float x0 = xs[kk * 36 + tx*2 + 0];
                float x1 = xs[kk * 36 + tx*2 + 1];
                acc[0][0] = fmaf(s0, x0, acc[0][0]);
                acc[0][1] = fmaf(s0, x1, acc[0][1]);
                acc[1][0] = fmaf(s1, x0, acc[1][0]);
                acc[1][1] = fmaf(s1, x1, acc[1][1]);
            }
            float eq0 = expf(acs_s[b32 + ty*2 + 0] - base);
            float eq1 = expf(acs_s[b32 + ty*2 + 1] - base);
            for (int n = 0; n < NS; n++) {
                float c0 = Cs[(ty*2+0) * 68 + n] * eq0;
                float c1 = Cs[(ty*2+1) * 68 + n] * eq1;
                float h0 = H[(tx*2+0) * 65 + n];
                float h1 = H[(tx*2+1) * 65 + n];
                acc[0][0] = fmaf(c0, h0, acc[0][0]);
                acc[0][1] = fmaf(c0, h1, acc[0][1]);
                acc[1][0] = fmaf(c1, h0, acc[1][0]);
                acc[1][1] = fmaf(c1, h1, acc[1][1]);
            }
            float xq00 = xs[(ty*2+0) * 36 + tx*2 + 0];
            float xq01 = xs[(ty*2+0) * 36 + tx*2 + 1];
            float xq10 = xs[(ty*2+1) * 36 + tx*2 + 0];
            float xq11 = xs[(ty*2+1) * 36 + tx*2 + 1];
            float2 w0, w1;
            w0.x = (acc[0][0] + Dh * xq00) * (pZ0.x / (1.f + expf(-pZ0.x)));
            w0.y = (acc[0][1] + Dh * xq01) * (pZ0.y / (1.f + expf(-pZ0.y)));
            w1.x = (acc[1][0] + Dh * xq10) * (pZ1.x / (1.f + expf(-pZ1.x)));
            w1.y = (acc[1][1] + Dh * xq11) * (pZ1.y / (1.f + expf(-pZ1.y)));
            *(float2*)(zy + (rowbase + b32 + ty*2 + 0) * DPROJ + h * HD + p0 + tx*2) = w0;
            *(float2*)(zy + (rowbase + b32 + ty*2 + 1) * DPROJ + h * HD + p0 + tx*2) = w1;
        }
        __syncthreads();   // all H reads done

        // ---- phase 4: H <- decay·H + B^T(coef·x)
        {
            float decay = expf(aL - base);
            float hreg[2][4];
            #pragma unroll
            for (int i = 0; i < 2; i++)
                #pragma unroll
                for (int j = 0; j < 4; j++)
                    hreg[i][j] = H[(ty*2+i) * 65 + tx*4 + j] * decay;
            for (int t = 0; t < 32; t++) {
                float cf = coefs[t];
                float b0 = Bsh[t * 68 + tx*4 + 0];
                float b1 = Bsh[t * 68 + tx*4 + 1];
                float b2 = Bsh[t * 68 + tx*4 + 2];
                float b3 = Bsh[t * 68 + tx*4 + 3];
                float xa = xs[t * 36 + ty*2 + 0] * cf;
                float xb = xs[t * 36 + ty*2 + 1] * cf;
                hreg[0][0] = fmaf(xa, b0, hreg[0][0]);
                hreg[0][1] = fmaf(xa, b1, hreg[0][1]);
                hreg[0][2] = fmaf(xa, b2, hreg[0][2]);
                hreg[0][3] = fmaf(xa, b3, hreg[0][3]);
                hreg[1][0] = fmaf(xb, b0, hreg[1][0]);
                hreg[1][1] = fmaf(xb, b1, hreg[1][1]);
                hreg[1][2] = fmaf(xb, b2, hreg[1][2]);
                hreg[1][3] = fmaf(xb, b3, hreg[1][3]);
            }
            #pragma unroll
            for (int i = 0; i < 2; i++)
                #pragma unroll
                for (int j = 0; j < 4; j++)
                    H[(ty*2+i) * 65 + tx*4 + j] = hreg[i][j];
        }
        __syncthreads();
    }
}

extern "C" void kernel_launch(void* const* d_in, const int* in_sizes, int n_in,
                              void* d_out, int out_size, void* d_ws, size_t ws_size,
                              hipStream_t stream)
{
    const float* x       = (const float*)d_in[0];
    const float* W_in    = (const float*)d_in[1];
    const float* conv_w  = (const float*)d_in[2];
    const float* conv_b  = (const float*)d_in[3];
    const float* A_log   = (const float*)d_in[4];
    const float* dt_bias = (const float*)d_in[5];
    const float* D_skip  = (const float*)d_in[6];
    const float* W_out   = (const float*)d_in[7];
    float* out = (float*)d_out;

    // per-batch workspace (~109 MB total)
    float* proj   = (float*)d_ws;                          // L_*DPROJ
    float* xbc    = proj   + (size_t)L_ * DPROJ;           // L_*CONVD
    float* dt_t   = xbc    + (size_t)L_ * CONVD;           // NC*NH*T_
    float* acs    = dt_t   + (size_t)NC * NH * T_;
    float* states = acs    + (size_t)NC * NH * T_;         // NC*NH*HD*NS

    dim3 blk(256);
    for (int b = 0; b < B_; b++) {
        const float* xb = x + (size_t)b * L_ * DM;
        float* outb = out + (size_t)b * L_ * DM;
        sgemm_abt<<<dim3((DPROJ + 127) / 128, L_ / 128), blk, 0, stream>>>(
            xb, W_in, proj, L_, DPROJ, DM, DM, DM, DPROJ);
        conv_silu<<<dim3((unsigned)(((size_t)L_ * CONVD + 255) / 256)), blk, 0, stream>>>(
            proj, conv_w, conv_b, xbc);
        dt_scan<<<dim3(NC * NH), blk, 0, stream>>>(proj, A_log, dt_bias, dt_t, acs);
        chunk_states<<<dim3(NC * NH), blk, 0, stream>>>(xbc, dt_t, acs, states);
        prev_rec<<<dim3(NH * 4), blk, 0, stream>>>(states, acs);
        y_chunk<<<dim3(NC * NH * 4), blk, 0, stream>>>(xbc, dt_t, acs, states, D_skip, proj);
        sgemm_abt<<<dim3(DM / 128, L_ / 128), blk, 0, stream>>>(
            proj, W_out, outb, L_, DM, DI, DPROJ, DI, DM);
    }
}

// Round 6
// 3241.457 us; speedup vs baseline: 1.1579x; 1.1579x over previous
//
#include <hip/hip_runtime.h>

#define B_     2
#define L_     4096
#define DM     1024
#define DI     2048
#define NH     16
#define HD     128
#define NS     64      // D_STATE
#define T_     256     // CHUNK
#define NC     16      // L_/T_
#define CONVD  2176    // DI + 2*NS
#define DPROJ  4240    // DI + CONVD + NH

// ---------------- generic C[m,n] = sum_k A[m,k]*B[n,k] (both row-major) ----------------
// single LDS buffer, 2 barriers/k-step (round-4 measured-good version; dbuf regressed r5)
__global__ __launch_bounds__(256) void sgemm_abt(
    const float* __restrict__ A, const float* __restrict__ Bm, float* __restrict__ C,
    int M, int N, int K, int lda, int ldb, int ldc)
{
    const int BM = 128, BN = 128, BK = 16;
    __shared__ __align__(16) float As[BK][BM];
    __shared__ __align__(16) float Bs[BK][BN];
    int tid = threadIdx.x;
    int m0 = blockIdx.y * BM;
    int n0 = blockIdx.x * BN;
    int ty = tid / 16, tx = tid % 16;

    float acc[8][8];
    #pragma unroll
    for (int i = 0; i < 8; i++)
        #pragma unroll
        for (int j = 0; j < 8; j++) acc[i][j] = 0.f;

    for (int k0 = 0; k0 < K; k0 += BK) {
        #pragma unroll
        for (int i = 0; i < 2; i++) {
            int f = tid * 2 + i;
            int row = f >> 2;
            int colv = f & 3;
            float4 av = *(const float4*)(A + (size_t)(m0 + row) * lda + k0 + colv * 4);
            As[colv*4+0][row] = av.x; As[colv*4+1][row] = av.y;
            As[colv*4+2][row] = av.z; As[colv*4+3][row] = av.w;
        }
        #pragma unroll
        for (int i = 0; i < 2; i++) {
            int f = tid * 2 + i;
            int row = f >> 2;
            int colv = f & 3;
            float4 bv = make_float4(0.f, 0.f, 0.f, 0.f);
            if (n0 + row < N)
                bv = *(const float4*)(Bm + (size_t)(n0 + row) * ldb + k0 + colv * 4);
            Bs[colv*4+0][row] = bv.x; Bs[colv*4+1][row] = bv.y;
            Bs[colv*4+2][row] = bv.z; Bs[colv*4+3][row] = bv.w;
        }
        __syncthreads();
        #pragma unroll
        for (int kk = 0; kk < BK; kk++) {
            float4 a0 = *(const float4*)&As[kk][ty*8];
            float4 a1 = *(const float4*)&As[kk][ty*8+4];
            float4 b0 = *(const float4*)&Bs[kk][tx*4];
            float4 b1 = *(const float4*)&Bs[kk][64 + tx*4];
            float a[8] = {a0.x,a0.y,a0.z,a0.w,a1.x,a1.y,a1.z,a1.w};
            float b[8] = {b0.x,b0.y,b0.z,b0.w,b1.x,b1.y,b1.z,b1.w};
            #pragma unroll
            for (int i = 0; i < 8; i++)
                #pragma unroll
                for (int j = 0; j < 8; j++)
                    acc[i][j] = fmaf(a[i], b[j], acc[i][j]);
        }
        __syncthreads();
    }
    #pragma unroll
    for (int i = 0; i < 8; i++) {
        int m = m0 + ty*8 + i;
        #pragma unroll
        for (int j = 0; j < 8; j++) {
            int n = n0 + ((j < 4) ? (tx*4 + j) : (64 + tx*4 + j - 4));
            if (n < N) C[(size_t)m * ldc + n] = acc[i][j];
        }
    }
}

// ---------------- depthwise causal conv (width 4) + bias + silu; one batch ----------------
__global__ void conv_silu(const float* __restrict__ proj, const float* __restrict__ w,
                          const float* __restrict__ bias, float* __restrict__ xbc)
{
    size_t idx = (size_t)blockIdx.x * 256 + threadIdx.x;
    if (idx >= (size_t)L_ * CONVD) return;
    int c = (int)(idx % CONVD);
    int l = (int)(idx / CONVD);
    float acc = bias[c];
    #pragma unroll
    for (int j = 0; j < 4; j++) {
        int ll = l - 3 + j;
        if (ll >= 0)
            acc = fmaf(proj[(size_t)ll * DPROJ + DI + c], w[c*4+j], acc);
    }
    acc = acc / (1.f + expf(-acc));   // silu
    xbc[(size_t)l * CONVD + c] = acc;
}

// ---------------- dt = softplus(dt_raw + bias); acs = cumsum(dt*A) within 256-chunk ----------------
__global__ __launch_bounds__(256) void dt_scan(
    const float* __restrict__ proj, const float* __restrict__ A_log,
    const float* __restrict__ dt_bias, float* __restrict__ dt_t, float* __restrict__ acs)
{
    int blk = blockIdx.x;            // c*NH + h
    int h = blk % NH;
    int c = blk / NH;
    int t = threadIdx.x;
    size_t row = (size_t)(c * T_ + t);
    float raw = proj[row * DPROJ + DI + CONVD + h] + dt_bias[h];
    float dtv = (raw > 20.f) ? raw : log1pf(expf(raw));
    float Ah = -expf(A_log[h]);
    __shared__ float buf[T_];
    buf[t] = dtv * Ah;
    __syncthreads();
    for (int off = 1; off < T_; off <<= 1) {
        float add = (t >= off) ? buf[t - off] : 0.f;
        __syncthreads();
        buf[t] += add;
        __syncthreads();
    }
    size_t o = (size_t)blk * T_ + t;
    dt_t[o] = dtv;
    acs[o]  = buf[t];
}

// ---------------- per-256-chunk states[p][n] = sum_t x[t,p]*B[t,n]*exp(acs_last-acs[t])*dt[t] ----------------
__global__ __launch_bounds__(256) void chunk_states(
    const float* __restrict__ xbc, const float* __restrict__ dt_t,
    const float* __restrict__ acs, float* __restrict__ states)
{
    int blk = blockIdx.x;            // c*NH + h
    int h = blk % NH;
    int c = blk / NH;
    int tid = threadIdx.x;
    __shared__ float coef[T_];
    __shared__ __align__(16) float xs[32][HD];
    __shared__ float Bs[32][NS + 1];
    {
        size_t o = (size_t)blk * T_;
        float last = acs[o + T_ - 1];
        coef[tid] = expf(last - acs[o + tid]) * dt_t[o + tid];
    }
    __syncthreads();
    int tx = tid % 16;   // n0 = tx*4
    int ty = tid / 16;   // p0 = ty*8
    float acc[8][4];
    #pragma unroll
    for (int i = 0; i < 8; i++)
        #pragma unroll
        for (int j = 0; j < 4; j++) acc[i][j] = 0.f;
    size_t rowbase = (size_t)(c * T_);
    for (int t0 = 0; t0 < T_; t0 += 32) {
        #pragma unroll
        for (int i = 0; i < 4; i++) {
            int idx = tid + 256 * i;
            int r = idx >> 5, cv = idx & 31;
            float4 v = *(const float4*)(xbc + (rowbase + t0 + r) * CONVD + h * HD + cv * 4);
            *(float4*)&xs[r][cv * 4] = v;
        }
        #pragma unroll
        for (int i = 0; i < 2; i++) {
            int idx = tid + 256 * i;
            int r = idx >> 4, cv = idx & 15;
            float4 v = *(const float4*)(xbc + (rowbase + t0 + r) * CONVD + DI + cv * 4);
            float wc = coef[t0 + r];
            Bs[r][cv*4+0] = v.x * wc; Bs[r][cv*4+1] = v.y * wc;
            Bs[r][cv*4+2] = v.z * wc; Bs[r][cv*4+3] = v.w * wc;
        }
        __syncthreads();
        #pragma unroll
        for (int tt = 0; tt < 32; tt++) {
            float xv[8], bv[4];
            #pragma unroll
            for (int i = 0; i < 8; i++) xv[i] = xs[tt][ty*8+i];
            #pragma unroll
            for (int j = 0; j < 4; j++) bv[j] = Bs[tt][tx*4+j];
            #pragma unroll
            for (int i = 0; i < 8; i++)
                #pragma unroll
                for (int j = 0; j < 4; j++)
                    acc[i][j] = fmaf(xv[i], bv[j], acc[i][j]);
        }
        __syncthreads();
    }
    size_t base = (size_t)blk * HD * NS;
    #pragma unroll
    for (int i = 0; i < 8; i++)
        #pragma unroll
        for (int j = 0; j < 4; j++)
            states[base + (size_t)(ty*8+i) * NS + tx*4+j] = acc[i][j];
}

// ---------------- in-place inter-chunk recurrence: states[c] <- prev[c] ----------------
__global__ __launch_bounds__(256) void prev_rec(
    float* __restrict__ states, const float* __restrict__ acs)
{
    int blk = blockIdx.x;          // h*4 + pq
    int pq = blk % 4;
    int h = blk / 4;
    int tid = threadIdx.x;
    int s = tid * 8;
    int p = pq * 32 + s / NS;
    int n0 = s % NS;
    float run[8];
    #pragma unroll
    for (int j = 0; j < 8; j++) run[j] = 0.f;
    for (int c = 0; c < NC; c++) {
        size_t ch = (size_t)(c * NH + h);
        size_t off = ch * HD * NS + (size_t)p * NS + n0;
        float sv[8];
        #pragma unroll
        for (int j = 0; j < 8; j++) sv[j] = states[off + j];
        #pragma unroll
        for (int j = 0; j < 8; j++) states[off + j] = run[j];
        float f = expf(acs[ch * T_ + T_ - 1]);
        #pragma unroll
        for (int j = 0; j < 8; j++) run[j] = sv[j] + f * run[j];
    }
}

// ---------------- fused Y with running state H in LDS; 512 threads for full occupancy ----------------
// 1024 blocks x 8 waves, 36.7KB LDS -> 4 blocks/CU -> 32 waves/CU (100%); VGPR pinned <=64.
__global__ __launch_bounds__(512, 8) void y_chunk(
    const float* __restrict__ xbc, const float* __restrict__ dt_t,
    const float* __restrict__ acs, const float* __restrict__ prev,
    const float* __restrict__ D_skip, float* zy /* = proj */)
{
    int blk = blockIdx.x;          // ((c*NH)+h)*4 + pq
    int pq = blk & 3;
    int h = (blk >> 2) & 15;
    int c = blk >> 6;
    int tid = threadIdx.x;
    int tx = tid & 15;             // p pair / n quad
    int ty = tid >> 4;             // 0..31 : q row / p row
    int p0 = pq * 32;

    __shared__ __align__(16) float smem[9184];
    float* H     = smem;           // [32][65]
    float* Cs    = smem + 2080;    // [32][68]
    float* Bsh   = smem + 4256;    // [32][68]
    float* xs    = smem + 6432;    // [32][36]
    float* Ss    = smem + 7584;    // [32][33]
    float* acs_s = smem + 8640;    // [256]
    float* dts   = smem + 8896;    // [256]
    float* coefs = smem + 9152;    // [32]

    size_t bch = (size_t)(c * NH + h);
    size_t rowbase = (size_t)(c * T_);
    if (tid < 256) {
        acs_s[tid] = acs[bch * T_ + tid];
        dts[tid]   = dt_t[bch * T_ + tid];
    }

    // prefetch regs: every thread 1 float4 of B and C; tid<256 one float4 of x
    float4 pB, pC, pX;
    int cBC = tx * 4;                       // rBC = ty
    int rX = tid >> 3, cX = (tid & 7) * 4;  // valid for tid<256
    auto issue = [&](int s) {
        const float* base = xbc + (rowbase + s * 32) * CONVD;
        pB = *(const float4*)(base + (size_t)ty * CONVD + DI + cBC);
        pC = *(const float4*)(base + (size_t)ty * CONVD + DI + NS + cBC);
        if (tid < 256)
            pX = *(const float4*)(base + (size_t)rX * CONVD + h * HD + p0 + cX);
    };
    issue(0);

    // H init: prev[p0+p][n], 4 consecutive floats per thread
    {
        int p = ty, n4 = tx * 4;
        const float* src = prev + bch * (HD * NS) + (size_t)(p0 + p) * NS + n4;
        H[p*65 + n4 + 0] = src[0];
        H[p*65 + n4 + 1] = src[1];
        H[p*65 + n4 + 2] = src[2];
        H[p*65 + n4 + 3] = src[3];
    }
    __syncthreads();

    float Dh = D_skip[h];

    for (int s = 0; s < 8; s++) {
        int b32 = s * 32;
        float base = (s == 0) ? 0.f : acs_s[b32 - 1];
        float aL = acs_s[b32 + 31];

        // ---- phase 1: prefetched regs -> LDS
        *(float4*)&Bsh[ty * 68 + cBC] = pB;
        *(float4*)&Cs [ty * 68 + cBC] = pC;
        if (tid < 256) *(float4*)&xs[rX * 36 + cX] = pX;
        if (tid < 32)
            coefs[tid] = dts[b32 + tid] * expf(aL - acs_s[b32 + tid]);
        __syncthreads();

        if (s < 7) issue(s + 1);   // next sub-chunk loads, hidden under P2/P3
        // z-gate prefetch: row q=ty, cols p0+tx*2
        float2 pZ = *(const float2*)(zy + (rowbase + b32 + ty) * DPROJ + h * HD + p0 + tx*2);

        // ---- phase 2: S[q=ty][k=tx*2+ki] = (C·B)·exp(acs[q]-acs[k])·dt[k], q>=k
        {
            float sv0 = 0.f, sv1 = 0.f;
            for (int n = 0; n < NS; n++) {
                float cq = Cs[ty * 68 + n];
                sv0 = fmaf(cq, Bsh[(tx*2+0) * 68 + n], sv0);
                sv1 = fmaf(cq, Bsh[(tx*2+1) * 68 + n], sv1);
            }
            int k0 = tx * 2;
            float v0 = 0.f, v1 = 0.f;
            if (ty >= k0)
                v0 = sv0 * expf(acs_s[b32+ty] - acs_s[b32+k0]) * dts[b32+k0];
            if (ty >= k0+1)
                v1 = sv1 * expf(acs_s[b32+ty] - acs_s[b32+k0+1]) * dts[b32+k0+1];
            Ss[ty * 33 + k0]     = v0;
            Ss[ty * 33 + k0 + 1] = v1;
        }
        __syncthreads();

        // ---- phase 3: Y = S·x + eq·(C·H) + D·x, gate with prefetched z, write
        {
            float a0 = 0.f, a1 = 0.f;
            for (int kk = 0; kk < 32; kk++) {
                float sq = Ss[ty * 33 + kk];
                a0 = fmaf(sq, xs[kk*36 + tx*2 + 0], a0);
                a1 = fmaf(sq, xs[kk*36 + tx*2 + 1], a1);
            }
            float eq = expf(acs_s[b32 + ty] - base);
            for (int n = 0; n < NS; n++) {
                float cv = Cs[ty*68 + n] * eq;
                a0 = fmaf(cv, H[(tx*2+0)*65 + n], a0);
                a1 = fmaf(cv, H[(tx*2+1)*65 + n], a1);
            }
            float xq0 = xs[ty*36 + tx*2 + 0];
            float xq1 = xs[ty*36 + tx*2 + 1];
            float2 w;
            w.x = (a0 + Dh * xq0) * (pZ.x / (1.f + expf(-pZ.x)));
            w.y = (a1 + Dh * xq1) * (pZ.y / (1.f + expf(-pZ.y)));
            *(float2*)(zy + (rowbase + b32 + ty) * DPROJ + h * HD + p0 + tx*2) = w;
        }
        __syncthreads();   // all H reads done before update

        // ---- phase 4: H[p=ty][n=tx*4+j] <- decay·H + B^T(coef·x)
        {
            float decay = expf(aL - base);
            float h0 = H[ty*65 + tx*4+0] * decay;
            float h1 = H[ty*65 + tx*4+1] * decay;
            float h2 = H[ty*65 + tx*4+2] * decay;
            float h3 = H[ty*65 + tx*4+3] * decay;
            for (int t = 0; t < 32; t++) {
                float xa = xs[t*36 + ty] * coefs[t];
                h0 = fmaf(xa, Bsh[t*68 + tx*4+0], h0);
                h1 = fmaf(xa, Bsh[t*68 + tx*4+1], h1);
                h2 = fmaf(xa, Bsh[t*68 + tx*4+2], h2);
                h3 = fmaf(xa, Bsh[t*68 + tx*4+3], h3);
            }
            H[ty*65 + tx*4+0] = h0;
            H[ty*65 + tx*4+1] = h1;
            H[ty*65 + tx*4+2] = h2;
            H[ty*65 + tx*4+3] = h3;
        }
        __syncthreads();
    }
}

extern "C" void kernel_launch(void* const* d_in, const int* in_sizes, int n_in,
                              void* d_out, int out_size, void* d_ws, size_t ws_size,
                              hipStream_t stream)
{
    const float* x       = (const float*)d_in[0];
    const float* W_in    = (const float*)d_in[1];
    const float* conv_w  = (const float*)d_in[2];
    const float* conv_b  = (const float*)d_in[3];
    const float* A_log   = (const float*)d_in[4];
    const float* dt_bias = (const float*)d_in[5];
    const float* D_skip  = (const float*)d_in[6];
    const float* W_out   = (const float*)d_in[7];
    float* out = (float*)d_out;

    // per-batch workspace (~109 MB total)
    float* proj   = (float*)d_ws;                          // L_*DPROJ
    float* xbc    = proj   + (size_t)L_ * DPROJ;           // L_*CONVD
    float* dt_t   = xbc    + (size_t)L_ * CONVD;           // NC*NH*T_
    float* acs    = dt_t   + (size_t)NC * NH * T_;
    float* states = acs    + (size_t)NC * NH * T_;         // NC*NH*HD*NS

    dim3 blk(256);
    for (int b = 0; b < B_; b++) {
        const float* xb = x + (size_t)b * L_ * DM;
        float* outb = out + (size_t)b * L_ * DM;
        sgemm_abt<<<dim3((DPROJ + 127) / 128, L_ / 128), blk, 0, stream>>>(
            xb, W_in, proj, L_, DPROJ, DM, DM, DM, DPROJ);
        conv_silu<<<dim3((unsigned)(((size_t)L_ * CONVD + 255) / 256)), blk, 0, stream>>>(
            proj, conv_w, conv_b, xbc);
        dt_scan<<<dim3(NC * NH), blk, 0, stream>>>(proj, A_log, dt_bias, dt_t, acs);
        chunk_states<<<dim3(NC * NH), blk, 0, stream>>>(xbc, dt_t, acs, states);
        prev_rec<<<dim3(NH * 4), blk, 0, stream>>>(states, acs);
        y_chunk<<<dim3(NC * NH * 4), dim3(512), 0, stream>>>(xbc, dt_t, acs, states, D_skip, proj);
        sgemm_abt<<<dim3(DM / 128, L_ / 128), blk, 0, stream>>>(
            proj, W_out, outb, L_, DM, DI, DPROJ, DI, DM);
    }
}

// Round 7
// 1849.554 us; speedup vs baseline: 2.0293x; 1.7526x over previous
//
#include <hip/hip_runtime.h>

#define B_     2
#define L_     4096
#define DM     1024
#define DI     2048
#define NH     16
#define HD     128
#define NS     64      // D_STATE
#define T_     256     // CHUNK
#define NC     16      // L_/T_
#define CONVD  2176    // DI + 2*NS
#define DPROJ  4240    // DI + CONVD + NH

// ---------------- generic C[m,n] = sum_k A[m,k]*B[n,k] (both row-major) ----------------
__global__ __launch_bounds__(256) void sgemm_abt(
    const float* __restrict__ A, const float* __restrict__ Bm, float* __restrict__ C,
    int M, int N, int K, int lda, int ldb, int ldc)
{
    const int BM = 128, BN = 128, BK = 16;
    __shared__ __align__(16) float As[BK][BM];
    __shared__ __align__(16) float Bs[BK][BN];
    int tid = threadIdx.x;
    int m0 = blockIdx.y * BM;
    int n0 = blockIdx.x * BN;
    int ty = tid / 16, tx = tid % 16;

    float acc[8][8];
    #pragma unroll
    for (int i = 0; i < 8; i++)
        #pragma unroll
        for (int j = 0; j < 8; j++) acc[i][j] = 0.f;

    for (int k0 = 0; k0 < K; k0 += BK) {
        #pragma unroll
        for (int i = 0; i < 2; i++) {
            int f = tid * 2 + i;
            int row = f >> 2;
            int colv = f & 3;
            float4 av = *(const float4*)(A + (size_t)(m0 + row) * lda + k0 + colv * 4);
            As[colv*4+0][row] = av.x; As[colv*4+1][row] = av.y;
            As[colv*4+2][row] = av.z; As[colv*4+3][row] = av.w;
        }
        #pragma unroll
        for (int i = 0; i < 2; i++) {
            int f = tid * 2 + i;
            int row = f >> 2;
            int colv = f & 3;
            float4 bv = make_float4(0.f, 0.f, 0.f, 0.f);
            if (n0 + row < N)
                bv = *(const float4*)(Bm + (size_t)(n0 + row) * ldb + k0 + colv * 4);
            Bs[colv*4+0][row] = bv.x; Bs[colv*4+1][row] = bv.y;
            Bs[colv*4+2][row] = bv.z; Bs[colv*4+3][row] = bv.w;
        }
        __syncthreads();
        #pragma unroll
        for (int kk = 0; kk < BK; kk++) {
            float4 a0 = *(const float4*)&As[kk][ty*8];
            float4 a1 = *(const float4*)&As[kk][ty*8+4];
            float4 b0 = *(const float4*)&Bs[kk][tx*4];
            float4 b1 = *(const float4*)&Bs[kk][64 + tx*4];
            float a[8] = {a0.x,a0.y,a0.z,a0.w,a1.x,a1.y,a1.z,a1.w};
            float b[8] = {b0.x,b0.y,b0.z,b0.w,b1.x,b1.y,b1.z,b1.w};
            #pragma unroll
            for (int i = 0; i < 8; i++)
                #pragma unroll
                for (int j = 0; j < 8; j++)
                    acc[i][j] = fmaf(a[i], b[j], acc[i][j]);
        }
        __syncthreads();
    }
    #pragma unroll
    for (int i = 0; i < 8; i++) {
        int m = m0 + ty*8 + i;
        #pragma unroll
        for (int j = 0; j < 8; j++) {
            int n = n0 + ((j < 4) ? (tx*4 + j) : (64 + tx*4 + j - 4));
            if (n < N) C[(size_t)m * ldc + n] = acc[i][j];
        }
    }
}

// ---------------- depthwise causal conv (width 4) + bias + silu; one batch ----------------
__global__ void conv_silu(const float* __restrict__ proj, const float* __restrict__ w,
                          const float* __restrict__ bias, float* __restrict__ xbc)
{
    size_t idx = (size_t)blockIdx.x * 256 + threadIdx.x;
    if (idx >= (size_t)L_ * CONVD) return;
    int c = (int)(idx % CONVD);
    int l = (int)(idx / CONVD);
    float acc = bias[c];
    #pragma unroll
    for (int j = 0; j < 4; j++) {
        int ll = l - 3 + j;
        if (ll >= 0)
            acc = fmaf(proj[(size_t)ll * DPROJ + DI + c], w[c*4+j], acc);
    }
    acc = acc / (1.f + expf(-acc));   // silu
    xbc[(size_t)l * CONVD + c] = acc;
}

// ---------------- dt = softplus(dt_raw + bias); acs = cumsum(dt*A) within 256-chunk ----------------
__global__ __launch_bounds__(256) void dt_scan(
    const float* __restrict__ proj, const float* __restrict__ A_log,
    const float* __restrict__ dt_bias, float* __restrict__ dt_t, float* __restrict__ acs)
{
    int blk = blockIdx.x;            // c*NH + h
    int h = blk % NH;
    int c = blk / NH;
    int t = threadIdx.x;
    size_t row = (size_t)(c * T_ + t);
    float raw = proj[row * DPROJ + DI + CONVD + h] + dt_bias[h];
    float dtv = (raw > 20.f) ? raw : log1pf(expf(raw));
    float Ah = -expf(A_log[h]);
    __shared__ float buf[T_];
    buf[t] = dtv * Ah;
    __syncthreads();
    for (int off = 1; off < T_; off <<= 1) {
        float add = (t >= off) ? buf[t - off] : 0.f;
        __syncthreads();
        buf[t] += add;
        __syncthreads();
    }
    size_t o = (size_t)blk * T_ + t;
    dt_t[o] = dtv;
    acs[o]  = buf[t];
}

// ---------------- per-256-chunk states[p][n] = sum_t x[t,p]*B[t,n]*exp(acs_last-acs[t])*dt[t] ----------------
__global__ __launch_bounds__(256) void chunk_states(
    const float* __restrict__ xbc, const float* __restrict__ dt_t,
    const float* __restrict__ acs, float* __restrict__ states)
{
    int bid = blockIdx.x;            // XCD swizzle (grid 256, 256%8==0 -> bijective)
    int blk = (bid & 7) * 32 + (bid >> 3);
    int h = blk % NH;
    int c = blk / NH;
    int tid = threadIdx.x;
    __shared__ float coef[T_];
    __shared__ __align__(16) float xs[32][HD];
    __shared__ float Bs[32][NS + 1];
    {
        size_t o = (size_t)blk * T_;
        float last = acs[o + T_ - 1];
        coef[tid] = expf(last - acs[o + tid]) * dt_t[o + tid];
    }
    __syncthreads();
    int tx = tid % 16;   // n0 = tx*4
    int ty = tid / 16;   // p0 = ty*8
    float acc[8][4];
    #pragma unroll
    for (int i = 0; i < 8; i++)
        #pragma unroll
        for (int j = 0; j < 4; j++) acc[i][j] = 0.f;
    size_t rowbase = (size_t)(c * T_);
    for (int t0 = 0; t0 < T_; t0 += 32) {
        #pragma unroll
        for (int i = 0; i < 4; i++) {
            int idx = tid + 256 * i;
            int r = idx >> 5, cv = idx & 31;
            float4 v = *(const float4*)(xbc + (rowbase + t0 + r) * CONVD + h * HD + cv * 4);
            *(float4*)&xs[r][cv * 4] = v;
        }
        #pragma unroll
        for (int i = 0; i < 2; i++) {
            int idx = tid + 256 * i;
            int r = idx >> 4, cv = idx & 15;
            float4 v = *(const float4*)(xbc + (rowbase + t0 + r) * CONVD + DI + cv * 4);
            float wc = coef[t0 + r];
            Bs[r][cv*4+0] = v.x * wc; Bs[r][cv*4+1] = v.y * wc;
            Bs[r][cv*4+2] = v.z * wc; Bs[r][cv*4+3] = v.w * wc;
        }
        __syncthreads();
        #pragma unroll
        for (int tt = 0; tt < 32; tt++) {
            float xv[8], bv[4];
            #pragma unroll
            for (int i = 0; i < 8; i++) xv[i] = xs[tt][ty*8+i];
            #pragma unroll
            for (int j = 0; j < 4; j++) bv[j] = Bs[tt][tx*4+j];
            #pragma unroll
            for (int i = 0; i < 8; i++)
                #pragma unroll
                for (int j = 0; j < 4; j++)
                    acc[i][j] = fmaf(xv[i], bv[j], acc[i][j]);
        }
        __syncthreads();
    }
    size_t base = (size_t)blk * HD * NS;
    #pragma unroll
    for (int i = 0; i < 8; i++)
        #pragma unroll
        for (int j = 0; j < 4; j++)
            states[base + (size_t)(ty*8+i) * NS + tx*4+j] = acc[i][j];
}

// ---------------- in-place inter-chunk recurrence: states[c] <- prev[c] ----------------
__global__ __launch_bounds__(256) void prev_rec(
    float* __restrict__ states, const float* __restrict__ acs)
{
    int blk = blockIdx.x;          // h*4 + pq
    int pq = blk % 4;
    int h = blk / 4;
    int tid = threadIdx.x;
    int s = tid * 8;
    int p = pq * 32 + s / NS;
    int n0 = s % NS;
    float run[8];
    #pragma unroll
    for (int j = 0; j < 8; j++) run[j] = 0.f;
    for (int c = 0; c < NC; c++) {
        size_t ch = (size_t)(c * NH + h);
        size_t off = ch * HD * NS + (size_t)p * NS + n0;
        float sv[8];
        #pragma unroll
        for (int j = 0; j < 8; j++) sv[j] = states[off + j];
        #pragma unroll
        for (int j = 0; j < 8; j++) states[off + j] = run[j];
        float f = expf(acs[ch * T_ + T_ - 1]);
        #pragma unroll
        for (int j = 0; j < 8; j++) run[j] = sv[j] + f * run[j];
    }
}

// ---------------- fused Y: ONE block per (chunk,head), full HD=128, H[128][64] in LDS ----------------
// x/z read exactly once per block; B/C 16x logical but L2-shared via XCD swizzle.
// 512 thr, 72.25 KB LDS, grid 256 (1 block/CU).
__global__ __launch_bounds__(512, 2) void y_chunk(
    const float* __restrict__ xbc, const float* __restrict__ dt_t,
    const float* __restrict__ acs, const float* __restrict__ prev,
    const float* __restrict__ D_skip, float* zy /* = proj */)
{
    int bid = blockIdx.x;
    int l = (bid & 7) * 32 + (bid >> 3);   // XCD swizzle: XCD k gets chunks 2k,2k+1
    int h = l & 15;
    int c = l >> 4;
    int tid = threadIdx.x;

    __shared__ __align__(16) float smem[18496];
    float* H     = smem;            // [128][65]
    float* Cs    = smem + 8320;     // [32][68]
    float* Bsh   = smem + 10496;    // [32][68]
    float* xs    = smem + 12672;    // [32][132]
    float* Ss    = smem + 16896;    // [32][33]
    float* acs_s = smem + 17952;    // [256]
    float* dts   = smem + 18208;    // [256]
    float* coefs = smem + 18464;    // [32]

    size_t bch = (size_t)(c * NH + h);
    size_t rowbase = (size_t)(c * T_);
    if (tid < 256) {
        acs_s[tid] = acs[bch * T_ + tid];
        dts[tid]   = dt_t[bch * T_ + tid];
    }

    // prefetch regs: 1 float4 each of B,C; 2 float4 of x per thread
    float4 pB, pC, pX0, pX1;
    int rBC = tid >> 4, cBC = (tid & 15) * 4;
    int rX0 = tid >> 5, cX0 = (tid & 31) * 4;
    int rX1 = (tid + 512) >> 5;                 // cols same as cX0
    auto issue = [&](int s) {
        const float* base = xbc + (rowbase + s * 32) * CONVD;
        pB  = *(const float4*)(base + (size_t)rBC * CONVD + DI + cBC);
        pC  = *(const float4*)(base + (size_t)rBC * CONVD + DI + NS + cBC);
        pX0 = *(const float4*)(base + (size_t)rX0 * CONVD + h * HD + cX0);
        pX1 = *(const float4*)(base + (size_t)rX1 * CONVD + h * HD + cX0);
    };
    issue(0);

    // H init from prev: pp = tid>>2 (0..127), n0 = (tid&3)*16
    int pp = tid >> 2, n0 = (tid & 3) * 16;
    {
        const float* src = prev + bch * (HD * NS) + (size_t)pp * NS + n0;
        #pragma unroll
        for (int j4 = 0; j4 < 4; j4++) {
            float4 v = *(const float4*)(src + j4 * 4);
            H[pp*65 + n0 + j4*4 + 0] = v.x;
            H[pp*65 + n0 + j4*4 + 1] = v.y;
            H[pp*65 + n0 + j4*4 + 2] = v.z;
            H[pp*65 + n0 + j4*4 + 3] = v.w;
        }
    }
    __syncthreads();

    float Dh = D_skip[h];
    int q2 = tid & 15;           // phase3: q in {q2, q2+16}
    int p4 = (tid >> 4) * 4;     // phase3: p = p4..p4+3
    int kq = tid >> 4;           // phase2: q row (0..31)
    int kk0 = tid & 15;          // phase2: k in {kk0, kk0+16}

    for (int s = 0; s < 8; s++) {
        int b32 = s * 32;
        float base = (s == 0) ? 0.f : acs_s[b32 - 1];
        float aL = acs_s[b32 + 31];

        // ---- P1: prefetched regs -> LDS
        *(float4*)&Bsh[rBC * 68 + cBC]  = pB;
        *(float4*)&Cs [rBC * 68 + cBC]  = pC;
        *(float4*)&xs [rX0 * 132 + cX0] = pX0;
        *(float4*)&xs [rX1 * 132 + cX0] = pX1;
        if (tid < 32)
            coefs[tid] = dts[b32 + tid] * expf(aL - acs_s[b32 + tid]);
        __syncthreads();

        if (s < 7) issue(s + 1);   // next sub-chunk, hidden under P2/P3
        // z-gate prefetch (float4 per row, 2 rows)
        float4 pZ0 = *(const float4*)(zy + (rowbase + b32 + q2) * DPROJ + h * HD + p4);
        float4 pZ1 = *(const float4*)(zy + (rowbase + b32 + q2 + 16) * DPROJ + h * HD + p4);

        // ---- P2: S[kq][k] = (C·B)·exp(acs[q]-acs[k])·dt[k], q>=k
        {
            float sv0 = 0.f, sv1 = 0.f;
            for (int n = 0; n < NS; n++) {
                float cq = Cs[kq * 68 + n];
                sv0 = fmaf(cq, Bsh[kk0 * 68 + n], sv0);
                sv1 = fmaf(cq, Bsh[(kk0 + 16) * 68 + n], sv1);
            }
            float v0 = 0.f, v1 = 0.f;
            if (kq >= kk0)
                v0 = sv0 * expf(acs_s[b32+kq] - acs_s[b32+kk0]) * dts[b32+kk0];
            if (kq >= kk0+16)
                v1 = sv1 * expf(acs_s[b32+kq] - acs_s[b32+kk0+16]) * dts[b32+kk0+16];
            Ss[kq * 33 + kk0]      = v0;
            Ss[kq * 33 + kk0 + 16] = v1;
        }
        __syncthreads();

        // ---- P3: Y[q][p] = S·x + eq·(C·H) + D·x, gate, write (2q x 4p per thread)
        {
            float a00=0.f,a01=0.f,a02=0.f,a03=0.f;
            float a10=0.f,a11=0.f,a12=0.f,a13=0.f;
            for (int kk = 0; kk < 32; kk++) {
                float s0 = Ss[q2 * 33 + kk];
                float s1 = Ss[(q2+16) * 33 + kk];
                float x0 = xs[kk*132 + p4 + 0];
                float x1 = xs[kk*132 + p4 + 1];
                float x2 = xs[kk*132 + p4 + 2];
                float x3 = xs[kk*132 + p4 + 3];
                a00 = fmaf(s0,x0,a00); a01 = fmaf(s0,x1,a01);
                a02 = fmaf(s0,x2,a02); a03 = fmaf(s0,x3,a03);
                a10 = fmaf(s1,x0,a10); a11 = fmaf(s1,x1,a11);
                a12 = fmaf(s1,x2,a12); a13 = fmaf(s1,x3,a13);
            }
            float eq0 = expf(acs_s[b32 + q2] - base);
            float eq1 = expf(acs_s[b32 + q2 + 16] - base);
            for (int n = 0; n < NS; n++) {
                float c0 = Cs[q2*68 + n] * eq0;
                float c1 = Cs[(q2+16)*68 + n] * eq1;
                float h0 = H[(p4+0)*65 + n];
                float h1 = H[(p4+1)*65 + n];
                float h2 = H[(p4+2)*65 + n];
                float h3 = H[(p4+3)*65 + n];
                a00 = fmaf(c0,h0,a00); a01 = fmaf(c0,h1,a01);
                a02 = fmaf(c0,h2,a02); a03 = fmaf(c0,h3,a03);
                a10 = fmaf(c1,h0,a10); a11 = fmaf(c1,h1,a11);
                a12 = fmaf(c1,h2,a12); a13 = fmaf(c1,h3,a13);
            }
            float4 w0, w1;
            w0.x = (a00 + Dh * xs[q2*132 + p4+0]) * (pZ0.x / (1.f + expf(-pZ0.x)));
            w0.y = (a01 + Dh * xs[q2*132 + p4+1]) * (pZ0.y / (1.f + expf(-pZ0.y)));
            w0.z = (a02 + Dh * xs[q2*132 + p4+2]) * (pZ0.z / (1.f + expf(-pZ0.z)));
            w0.w = (a03 + Dh * xs[q2*132 + p4+3]) * (pZ0.w / (1.f + expf(-pZ0.w)));
            w1.x = (a10 + Dh * xs[(q2+16)*132 + p4+0]) * (pZ1.x / (1.f + expf(-pZ1.x)));
            w1.y = (a11 + Dh * xs[(q2+16)*132 + p4+1]) * (pZ1.y / (1.f + expf(-pZ1.y)));
            w1.z = (a12 + Dh * xs[(q2+16)*132 + p4+2]) * (pZ1.z / (1.f + expf(-pZ1.z)));
            w1.w = (a13 + Dh * xs[(q2+16)*132 + p4+3]) * (pZ1.w / (1.f + expf(-pZ1.w)));
            *(float4*)(zy + (rowbase + b32 + q2) * DPROJ + h * HD + p4)      = w0;
            *(float4*)(zy + (rowbase + b32 + q2 + 16) * DPROJ + h * HD + p4) = w1;
        }
        __syncthreads();   // all H reads done before update

        // ---- P4: H[pp][n0..n0+15] <- decay·H + B^T(coef·x)
        {
            float decay = expf(aL - base);
            float hreg[16];
            #pragma unroll
            for (int j = 0; j < 16; j++)
                hreg[j] = H[pp*65 + n0 + j] * decay;
            for (int t = 0; t < 32; t++) {
                float xa = xs[t*132 + pp] * coefs[t];
                #pragma unroll
                for (int j = 0; j < 16; j++)
                    hreg[j] = fmaf(xa, Bsh[t*68 + n0 + j], hreg[j]);
            }
            #pragma unroll
            for (int j = 0; j < 16; j++)
                H[pp*65 + n0 + j] = hreg[j];
        }
        __syncthreads();
    }
}

extern "C" void kernel_launch(void* const* d_in, const int* in_sizes, int n_in,
                              void* d_out, int out_size, void* d_ws, size_t ws_size,
                              hipStream_t stream)
{
    const float* x       = (const float*)d_in[0];
    const float* W_in    = (const float*)d_in[1];
    const float* conv_w  = (const float*)d_in[2];
    const float* conv_b  = (const float*)d_in[3];
    const float* A_log   = (const float*)d_in[4];
    const float* dt_bias = (const float*)d_in[5];
    const float* D_skip  = (const float*)d_in[6];
    const float* W_out   = (const float*)d_in[7];
    float* out = (float*)d_out;

    // per-batch workspace (~109 MB total)
    float* proj   = (float*)d_ws;                          // L_*DPROJ
    float* xbc    = proj   + (size_t)L_ * DPROJ;           // L_*CONVD
    float* dt_t   = xbc    + (size_t)L_ * CONVD;           // NC*NH*T_
    float* acs    = dt_t   + (size_t)NC * NH * T_;
    float* states = acs    + (size_t)NC * NH * T_;         // NC*NH*HD*NS

    dim3 blk(256);
    for (int b = 0; b < B_; b++) {
        const float* xb = x + (size_t)b * L_ * DM;
        float* outb = out + (size_t)b * L_ * DM;
        sgemm_abt<<<dim3((DPROJ + 127) / 128, L_ / 128), blk, 0, stream>>>(
            xb, W_in, proj, L_, DPROJ, DM, DM, DM, DPROJ);
        conv_silu<<<dim3((unsigned)(((size_t)L_ * CONVD + 255) / 256)), blk, 0, stream>>>(
            proj, conv_w, conv_b, xbc);
        dt_scan<<<dim3(NC * NH), blk, 0, stream>>>(proj, A_log, dt_bias, dt_t, acs);
        chunk_states<<<dim3(NC * NH), blk, 0, stream>>>(xbc, dt_t, acs, states);
        prev_rec<<<dim3(NH * 4), blk, 0, stream>>>(states, acs);
        y_chunk<<<dim3(NC * NH), dim3(512), 0, stream>>>(xbc, dt_t, acs, states, D_skip, proj);
        sgemm_abt<<<dim3(DM / 128, L_ / 128), blk, 0, stream>>>(
            proj, W_out, outb, L_, DM, DI, DPROJ, DI, DM);
    }
}

// Round 8
// 993.132 us; speedup vs baseline: 3.7793x; 1.8623x over previous
//
#include <hip/hip_runtime.h>

#define B_     2
#define L_     4096
#define DM     1024
#define DI     2048
#define NH     16
#define HD     128
#define NS     64      // D_STATE
#define T_     256     // CHUNK
#define NC     16      // L_/T_
#define CONVD  2176    // DI + 2*NS
#define DPROJ  4240    // DI + CONVD + NH

typedef __attribute__((ext_vector_type(8))) short bf16x8;
typedef __attribute__((ext_vector_type(4))) float f32x4;

// split fp32 -> bf16 hi (RNE) + bf16 lo (truncated residual)
__device__ __forceinline__ void bsplit(float x, unsigned short& h, unsigned short& l) {
    unsigned u = __float_as_uint(x);
    unsigned t = u + 0x7FFFu + ((u >> 16) & 1u);
    h = (unsigned short)(t >> 16);
    float lo = x - __uint_as_float(t & 0xFFFF0000u);
    l = (unsigned short)(__float_as_uint(lo) >> 16);
}

// ---------------- one-time weight split: W fp32 -> Wh/Wl bf16 ----------------
__global__ __launch_bounds__(256) void split_w(
    const float* __restrict__ W, unsigned short* __restrict__ Wh,
    unsigned short* __restrict__ Wl, int n4 /* n/4 */)
{
    int i = blockIdx.x * 256 + threadIdx.x;
    if (i >= n4) return;
    float4 v = *(const float4*)(W + (size_t)i * 4);
    ushort4 h, l;
    bsplit(v.x, h.x, l.x); bsplit(v.y, h.y, l.y);
    bsplit(v.z, h.z, l.z); bsplit(v.w, h.w, l.w);
    *(ushort4*)(Wh + (size_t)i * 4) = h;
    *(ushort4*)(Wl + (size_t)i * 4) = l;
}

// ---------------- C[m,n] = sum_k A[m,k]*W[n,k] via bf16x3 MFMA ----------------
// A fp32 (split on the fly), W pre-split bf16 hi/lo (ldb = K). 128x128 tile, BK=32.
__global__ __launch_bounds__(256) void mfma_gemm_abt(
    const float* __restrict__ A, const unsigned short* __restrict__ Wh,
    const unsigned short* __restrict__ Wl, float* __restrict__ C,
    int M, int N, int K, int lda, int ldc)
{
    __shared__ unsigned short AhL[128 * 40];
    __shared__ unsigned short AlL[128 * 40];
    __shared__ unsigned short BhL[128 * 40];
    __shared__ unsigned short BlL[128 * 40];

    int tid = threadIdx.x;
    int m0 = blockIdx.y * 128, n0 = blockIdx.x * 128;
    int lane = tid & 63, w = tid >> 6;
    int mblk = (w >> 1) * 64, nblk = (w & 1) * 64;
    int fr = lane & 15;            // fragment row (m or n within 16-tile)
    int fk = (lane >> 4) * 8;      // fragment k offset

    f32x4 acc[4][4];
    #pragma unroll
    for (int i = 0; i < 4; i++)
        #pragma unroll
        for (int j = 0; j < 4; j++) acc[i][j] = (f32x4){0.f, 0.f, 0.f, 0.f};

    for (int k0 = 0; k0 < K; k0 += 32) {
        __syncthreads();   // all frag reads of previous tile done
        #pragma unroll
        for (int i = 0; i < 4; i++) {
            int f = tid + 256 * i;
            int row = f >> 3, kv = (f & 7) * 4;
            // A: fp32 load + split
            float4 av = *(const float4*)(A + (size_t)(m0 + row) * lda + k0 + kv);
            ushort4 h, l;
            bsplit(av.x, h.x, l.x); bsplit(av.y, h.y, l.y);
            bsplit(av.z, h.z, l.z); bsplit(av.w, h.w, l.w);
            *(ushort4*)&AhL[row * 40 + kv] = h;
            *(ushort4*)&AlL[row * 40 + kv] = l;
            // B: pre-split bf16 copy
            ushort4 bh = {0, 0, 0, 0}, bl = {0, 0, 0, 0};
            if (n0 + row < N) {
                size_t off = (size_t)(n0 + row) * K + k0 + kv;
                bh = *(const ushort4*)(Wh + off);
                bl = *(const ushort4*)(Wl + off);
            }
            *(ushort4*)&BhL[row * 40 + kv] = bh;
            *(ushort4*)&BlL[row * 40 + kv] = bl;
        }
        __syncthreads();

        bf16x8 ah[4], al[4], bh[4], bl[4];
        #pragma unroll
        for (int t = 0; t < 4; t++) {
            ah[t] = *(const bf16x8*)&AhL[(mblk + t*16 + fr) * 40 + fk];
            al[t] = *(const bf16x8*)&AlL[(mblk + t*16 + fr) * 40 + fk];
            bh[t] = *(const bf16x8*)&BhL[(nblk + t*16 + fr) * 40 + fk];
            bl[t] = *(const bf16x8*)&BlL[(nblk + t*16 + fr) * 40 + fk];
        }
        #pragma unroll
        for (int mt = 0; mt < 4; mt++)
            #pragma unroll
            for (int nt = 0; nt < 4; nt++) {
                f32x4 a = acc[mt][nt];
                a = __builtin_amdgcn_mfma_f32_16x16x32_bf16(al[mt], bh[nt], a, 0, 0, 0);
                a = __builtin_amdgcn_mfma_f32_16x16x32_bf16(ah[mt], bl[nt], a, 0, 0, 0);
                a = __builtin_amdgcn_mfma_f32_16x16x32_bf16(ah[mt], bh[nt], a, 0, 0, 0);
                acc[mt][nt] = a;
            }
    }

    int crow = (lane >> 4) * 4;
    #pragma unroll
    for (int mt = 0; mt < 4; mt++) {
        int rbase = m0 + mblk + mt*16 + crow;
        #pragma unroll
        for (int nt = 0; nt < 4; nt++) {
            int col = n0 + nblk + nt*16 + fr;
            if (col < N) {
                #pragma unroll
                for (int i = 0; i < 4; i++)
                    C[(size_t)(rbase + i) * ldc + col] = acc[mt][nt][i];
            }
        }
    }
}

// ---------------- depthwise causal conv (width 4) + bias + silu; one batch ----------------
__global__ void conv_silu(const float* __restrict__ proj, const float* __restrict__ w,
                          const float* __restrict__ bias, float* __restrict__ xbc)
{
    size_t idx = (size_t)blockIdx.x * 256 + threadIdx.x;
    if (idx >= (size_t)L_ * CONVD) return;
    int c = (int)(idx % CONVD);
    int l = (int)(idx / CONVD);
    float acc = bias[c];
    #pragma unroll
    for (int j = 0; j < 4; j++) {
        int ll = l - 3 + j;
        if (ll >= 0)
            acc = fmaf(proj[(size_t)ll * DPROJ + DI + c], w[c*4+j], acc);
    }
    acc = acc / (1.f + expf(-acc));   // silu
    xbc[(size_t)l * CONVD + c] = acc;
}

// ---------------- dt = softplus(dt_raw + bias); acs = cumsum(dt*A) within 256-chunk ----------------
__global__ __launch_bounds__(256) void dt_scan(
    const float* __restrict__ proj, const float* __restrict__ A_log,
    const float* __restrict__ dt_bias, float* __restrict__ dt_t, float* __restrict__ acs)
{
    int blk = blockIdx.x;            // c*NH + h
    int h = blk % NH;
    int c = blk / NH;
    int t = threadIdx.x;
    size_t row = (size_t)(c * T_ + t);
    float raw = proj[row * DPROJ + DI + CONVD + h] + dt_bias[h];
    float dtv = (raw > 20.f) ? raw : log1pf(expf(raw));
    float Ah = -expf(A_log[h]);
    __shared__ float buf[T_];
    buf[t] = dtv * Ah;
    __syncthreads();
    for (int off = 1; off < T_; off <<= 1) {
        float add = (t >= off) ? buf[t - off] : 0.f;
        __syncthreads();
        buf[t] += add;
        __syncthreads();
    }
    size_t o = (size_t)blk * T_ + t;
    dt_t[o] = dtv;
    acs[o]  = buf[t];
}

// ---------------- per-256-chunk states[p][n] = sum_t x[t,p]*B[t,n]*exp(acs_last-acs[t])*dt[t] ----------------
__global__ __launch_bounds__(256) void chunk_states(
    const float* __restrict__ xbc, const float* __restrict__ dt_t,
    const float* __restrict__ acs, float* __restrict__ states)
{
    int bid = blockIdx.x;            // XCD swizzle (grid 256, 256%8==0 -> bijective)
    int blk = (bid & 7) * 32 + (bid >> 3);
    int h = blk % NH;
    int c = blk / NH;
    int tid = threadIdx.x;
    __shared__ float coef[T_];
    __shared__ __align__(16) float xs[32][HD];
    __shared__ float Bs[32][NS + 1];
    {
        size_t o = (size_t)blk * T_;
        float last = acs[o + T_ - 1];
        coef[tid] = expf(last - acs[o + tid]) * dt_t[o + tid];
    }
    __syncthreads();
    int tx = tid % 16;   // n0 = tx*4
    int ty = tid / 16;   // p0 = ty*8
    float acc[8][4];
    #pragma unroll
    for (int i = 0; i < 8; i++)
        #pragma unroll
        for (int j = 0; j < 4; j++) acc[i][j] = 0.f;
    size_t rowbase = (size_t)(c * T_);
    for (int t0 = 0; t0 < T_; t0 += 32) {
        #pragma unroll
        for (int i = 0; i < 4; i++) {
            int idx = tid + 256 * i;
            int r = idx >> 5, cv = idx & 31;
            float4 v = *(const float4*)(xbc + (rowbase + t0 + r) * CONVD + h * HD + cv * 4);
            *(float4*)&xs[r][cv * 4] = v;
        }
        #pragma unroll
        for (int i = 0; i < 2; i++) {
            int idx = tid + 256 * i;
            int r = idx >> 4, cv = idx & 15;
            float4 v = *(const float4*)(xbc + (rowbase + t0 + r) * CONVD + DI + cv * 4);
            float wc = coef[t0 + r];
            Bs[r][cv*4+0] = v.x * wc; Bs[r][cv*4+1] = v.y * wc;
            Bs[r][cv*4+2] = v.z * wc; Bs[r][cv*4+3] = v.w * wc;
        }
        __syncthreads();
        #pragma unroll
        for (int tt = 0; tt < 32; tt++) {
            float xv[8], bv[4];
            #pragma unroll
            for (int i = 0; i < 8; i++) xv[i] = xs[tt][ty*8+i];
            #pragma unroll
            for (int j = 0; j < 4; j++) bv[j] = Bs[tt][tx*4+j];
            #pragma unroll
            for (int i = 0; i < 8; i++)
                #pragma unroll
                for (int j = 0; j < 4; j++)
                    acc[i][j] = fmaf(xv[i], bv[j], acc[i][j]);
        }
        __syncthreads();
    }
    size_t base = (size_t)blk * HD * NS;
    #pragma unroll
    for (int i = 0; i < 8; i++)
        #pragma unroll
        for (int j = 0; j < 4; j++)
            states[base + (size_t)(ty*8+i) * NS + tx*4+j] = acc[i][j];
}

// ---------------- in-place inter-chunk recurrence: states[c] <- prev[c] ----------------
__global__ __launch_bounds__(256) void prev_rec(
    float* __restrict__ states, const float* __restrict__ acs)
{
    int blk = blockIdx.x;          // h*4 + pq
    int pq = blk % 4;
    int h = blk / 4;
    int tid = threadIdx.x;
    int s = tid * 8;
    int p = pq * 32 + s / NS;
    int n0 = s % NS;
    float run[8];
    #pragma unroll
    for (int j = 0; j < 8; j++) run[j] = 0.f;
    for (int c = 0; c < NC; c++) {
        size_t ch = (size_t)(c * NH + h);
        size_t off = ch * HD * NS + (size_t)p * NS + n0;
        float sv[8];
        #pragma unroll
        for (int j = 0; j < 8; j++) sv[j] = states[off + j];
        #pragma unroll
        for (int j = 0; j < 8; j++) states[off + j] = run[j];
        float f = expf(acs[ch * T_ + T_ - 1]);
        #pragma unroll
        for (int j = 0; j < 8; j++) run[j] = sv[j] + f * run[j];
    }
}

// ---------------- fused Y: ONE block per (chunk,head), full HD=128, H[128][64] in LDS ----------------
__global__ __launch_bounds__(512, 2) void y_chunk(
    const float* __restrict__ xbc, const float* __restrict__ dt_t,
    const float* __restrict__ acs, const float* __restrict__ prev,
    const float* __restrict__ D_skip, float* zy /* = proj */)
{
    int bid = blockIdx.x;
    int l = (bid & 7) * 32 + (bid >> 3);   // XCD swizzle
    int h = l & 15;
    int c = l >> 4;
    int tid = threadIdx.x;

    __shared__ __align__(16) float smem[18496];
    float* H     = smem;            // [128][65]
    float* Cs    = smem + 8320;     // [32][68]
    float* Bsh   = smem + 10496;    // [32][68]
    float* xs    = smem + 12672;    // [32][132]
    float* Ss    = smem + 16896;    // [32][33]
    float* acs_s = smem + 17952;    // [256]
    float* dts   = smem + 18208;    // [256]
    float* coefs = smem + 18464;    // [32]

    size_t bch = (size_t)(c * NH + h);
    size_t rowbase = (size_t)(c * T_);
    if (tid < 256) {
        acs_s[tid] = acs[bch * T_ + tid];
        dts[tid]   = dt_t[bch * T_ + tid];
    }

    float4 pB, pC, pX0, pX1;
    int rBC = tid >> 4, cBC = (tid & 15) * 4;
    int rX0 = tid >> 5, cX0 = (tid & 31) * 4;
    int rX1 = (tid + 512) >> 5;
    auto issue = [&](int s) {
        const float* base = xbc + (rowbase + s * 32) * CONVD;
        pB  = *(const float4*)(base + (size_t)rBC * CONVD + DI + cBC);
        pC  = *(const float4*)(base + (size_t)rBC * CONVD + DI + NS + cBC);
        pX0 = *(const float4*)(base + (size_t)rX0 * CONVD + h * HD + cX0);
        pX1 = *(const float4*)(base + (size_t)rX1 * CONVD + h * HD + cX0);
    };
    issue(0);

    int pp = tid >> 2, n0 = (tid & 3) * 16;
    {
        const float* src = prev + bch * (HD * NS) + (size_t)pp * NS + n0;
        #pragma unroll
        for (int j4 = 0; j4 < 4; j4++) {
            float4 v = *(const float4*)(src + j4 * 4);
            H[pp*65 + n0 + j4*4 + 0] = v.x;
            H[pp*65 + n0 + j4*4 + 1] = v.y;
            H[pp*65 + n0 + j4*4 + 2] = v.z;
            H[pp*65 + n0 + j4*4 + 3] = v.w;
        }
    }
    __syncthreads();

    float Dh = D_skip[h];
    int q2 = tid & 15;
    int p4 = (tid >> 4) * 4;
    int kq = tid >> 4;
    int kk0 = tid & 15;

    for (int s = 0; s < 8; s++) {
        int b32 = s * 32;
        float base = (s == 0) ? 0.f : acs_s[b32 - 1];
        float aL = acs_s[b32 + 31];

        *(float4*)&Bsh[rBC * 68 + cBC]  = pB;
        *(float4*)&Cs [rBC * 68 + cBC]  = pC;
        *(float4*)&xs [rX0 * 132 + cX0] = pX0;
        *(float4*)&xs [rX1 * 132 + cX0] = pX1;
        if (tid < 32)
            coefs[tid] = dts[b32 + tid] * expf(aL - acs_s[b32 + tid]);
        __syncthreads();

        if (s < 7) issue(s + 1);
        float4 pZ0 = *(const float4*)(zy + (rowbase + b32 + q2) * DPROJ + h * HD + p4);
        float4 pZ1 = *(const float4*)(zy + (rowbase + b32 + q2 + 16) * DPROJ + h * HD + p4);

        {
            float sv0 = 0.f, sv1 = 0.f;
            for (int n = 0; n < NS; n++) {
                float cq = Cs[kq * 68 + n];
                sv0 = fmaf(cq, Bsh[kk0 * 68 + n], sv0);
                sv1 = fmaf(cq, Bsh[(kk0 + 16) * 68 + n], sv1);
            }
            float v0 = 0.f, v1 = 0.f;
            if (kq >= kk0)
                v0 = sv0 * expf(acs_s[b32+kq] - acs_s[b32+kk0]) * dts[b32+kk0];
            if (kq >= kk0+16)
                v1 = sv1 * expf(acs_s[b32+kq] - acs_s[b32+kk0+16]) * dts[b32+kk0+16];
            Ss[kq * 33 + kk0]      = v0;
            Ss[kq * 33 + kk0 + 16] = v1;
        }
        __syncthreads();

        {
            float a00=0.f,a01=0.f,a02=0.f,a03=0.f;
            float a10=0.f,a11=0.f,a12=0.f,a13=0.f;
            for (int kk = 0; kk < 32; kk++) {
                float s0 = Ss[q2 * 33 + kk];
                float s1 = Ss[(q2+16) * 33 + kk];
                float x0 = xs[kk*132 + p4 + 0];
                float x1 = xs[kk*132 + p4 + 1];
                float x2 = xs[kk*132 + p4 + 2];
                float x3 = xs[kk*132 + p4 + 3];
                a00 = fmaf(s0,x0,a00); a01 = fmaf(s0,x1,a01);
                a02 = fmaf(s0,x2,a02); a03 = fmaf(s0,x3,a03);
                a10 = fmaf(s1,x0,a10); a11 = fmaf(s1,x1,a11);
                a12 = fmaf(s1,x2,a12); a13 = fmaf(s1,x3,a13);
            }
            float eq0 = expf(acs_s[b32 + q2] - base);
            float eq1 = expf(acs_s[b32 + q2 + 16] - base);
            for (int n = 0; n < NS; n++) {
                float c0 = Cs[q2*68 + n] * eq0;
                float c1 = Cs[(q2+16)*68 + n] * eq1;
                float h0 = H[(p4+0)*65 + n];
                float h1 = H[(p4+1)*65 + n];
                float h2 = H[(p4+2)*65 + n];
                float h3 = H[(p4+3)*65 + n];
                a00 = fmaf(c0,h0,a00); a01 = fmaf(c0,h1,a01);
                a02 = fmaf(c0,h2,a02); a03 = fmaf(c0,h3,a03);
                a10 = fmaf(c1,h0,a10); a11 = fmaf(c1,h1,a11);
                a12 = fmaf(c1,h2,a12); a13 = fmaf(c1,h3,a13);
            }
            float4 w0, w1;
            w0.x = (a00 + Dh * xs[q2*132 + p4+0]) * (pZ0.x / (1.f + expf(-pZ0.x)));
            w0.y = (a01 + Dh * xs[q2*132 + p4+1]) * (pZ0.y / (1.f + expf(-pZ0.y)));
            w0.z = (a02 + Dh * xs[q2*132 + p4+2]) * (pZ0.z / (1.f + expf(-pZ0.z)));
            w0.w = (a03 + Dh * xs[q2*132 + p4+3]) * (pZ0.w / (1.f + expf(-pZ0.w)));
            w1.x = (a10 + Dh * xs[(q2+16)*132 + p4+0]) * (pZ1.x / (1.f + expf(-pZ1.x)));
            w1.y = (a11 + Dh * xs[(q2+16)*132 + p4+1]) * (pZ1.y / (1.f + expf(-pZ1.y)));
            w1.z = (a12 + Dh * xs[(q2+16)*132 + p4+2]) * (pZ1.z / (1.f + expf(-pZ1.z)));
            w1.w = (a13 + Dh * xs[(q2+16)*132 + p4+3]) * (pZ1.w / (1.f + expf(-pZ1.w)));
            *(float4*)(zy + (rowbase + b32 + q2) * DPROJ + h * HD + p4)      = w0;
            *(float4*)(zy + (rowbase + b32 + q2 + 16) * DPROJ + h * HD + p4) = w1;
        }
        __syncthreads();

        {
            float decay = expf(aL - base);
            float hreg[16];
            #pragma unroll
            for (int j = 0; j < 16; j++)
                hreg[j] = H[pp*65 + n0 + j] * decay;
            for (int t = 0; t < 32; t++) {
                float xa = xs[t*132 + pp] * coefs[t];
                #pragma unroll
                for (int j = 0; j < 16; j++)
                    hreg[j] = fmaf(xa, Bsh[t*68 + n0 + j], hreg[j]);
            }
            #pragma unroll
            for (int j = 0; j < 16; j++)
                H[pp*65 + n0 + j] = hreg[j];
        }
        __syncthreads();
    }
}

extern "C" void kernel_launch(void* const* d_in, const int* in_sizes, int n_in,
                              void* d_out, int out_size, void* d_ws, size_t ws_size,
                              hipStream_t stream)
{
    const float* x       = (const float*)d_in[0];
    const float* W_in    = (const float*)d_in[1];
    const float* conv_w  = (const float*)d_in[2];
    const float* conv_b  = (const float*)d_in[3];
    const float* A_log   = (const float*)d_in[4];
    const float* dt_bias = (const float*)d_in[5];
    const float* D_skip  = (const float*)d_in[6];
    const float* W_out   = (const float*)d_in[7];
    float* out = (float*)d_out;

    // workspace (~135 MB)
    float* proj   = (float*)d_ws;                          // L_*DPROJ
    float* xbc    = proj   + (size_t)L_ * DPROJ;           // L_*CONVD
    float* dt_t   = xbc    + (size_t)L_ * CONVD;           // NC*NH*T_
    float* acs    = dt_t   + (size_t)NC * NH * T_;
    float* states = acs    + (size_t)NC * NH * T_;         // NC*NH*HD*NS
    unsigned short* WinH  = (unsigned short*)(states + (size_t)NC * NH * HD * NS);
    unsigned short* WinL  = WinH + (size_t)DPROJ * DM;
    unsigned short* WoutH = WinL + (size_t)DPROJ * DM;
    unsigned short* WoutL = WoutH + (size_t)DM * DI;

    dim3 blk(256);
    {   // one-time weight splits
        int n4in = (DPROJ * DM) / 4;
        split_w<<<dim3((n4in + 255) / 256), blk, 0, stream>>>(W_in, WinH, WinL, n4in);
        int n4out = (DM * DI) / 4;
        split_w<<<dim3((n4out + 255) / 256), blk, 0, stream>>>(W_out, WoutH, WoutL, n4out);
    }

    for (int b = 0; b < B_; b++) {
        const float* xb = x + (size_t)b * L_ * DM;
        float* outb = out + (size_t)b * L_ * DM;
        mfma_gemm_abt<<<dim3((DPROJ + 127) / 128, L_ / 128), blk, 0, stream>>>(
            xb, WinH, WinL, proj, L_, DPROJ, DM, DM, DPROJ);
        conv_silu<<<dim3((unsigned)(((size_t)L_ * CONVD + 255) / 256)), blk, 0, stream>>>(
            proj, conv_w, conv_b, xbc);
        dt_scan<<<dim3(NC * NH), blk, 0, stream>>>(proj, A_log, dt_bias, dt_t, acs);
        chunk_states<<<dim3(NC * NH), blk, 0, stream>>>(xbc, dt_t, acs, states);
        prev_rec<<<dim3(NH * 4), blk, 0, stream>>>(states, acs);
        y_chunk<<<dim3(NC * NH), dim3(512), 0, stream>>>(xbc, dt_t, acs, states, D_skip, proj);
        mfma_gemm_abt<<<dim3(DM / 128, L_ / 128), blk, 0, stream>>>(
            proj, WoutH, WoutL, outb, L_, DM, DI, DPROJ, DM);
    }
}